// Round 18
// baseline (11686.313 us; speedup 1.0000x reference)
//
#include <hip/hip_runtime.h>
#include <cstddef>

#define BB 256   // batch
#define TT 4096  // time steps
#define HH 64    // hidden
#define NT 256   // 4 waves; wave w owns units 16w..16w+15 (all 4 gates)
#define CH 4     // chunk depth (steps)
#define NCH (TT / CH)
#define NG 128   // batch groups of 2 -> grid 512 = 2 blocks/CU co-resident
#define LOG2E 1.442695041f

typedef __attribute__((ext_vector_type(8))) short short8;   // 8 bf16 (4 VGPR)
typedef __attribute__((ext_vector_type(4))) short short4v;  // 4 bf16 (2 VGPR)
typedef __attribute__((ext_vector_type(4))) float floatx4;

// produced-chunk counters: consumer (l,gb) polls row l-1.
__device__ int g_flags[3 * NG];
__global__ void zero_flags_kernel() { g_flags[threadIdx.x] = 0; }

__device__ __forceinline__ floatx4 mfma16(short8 a, short8 b, floatx4 c) {
    return __builtin_amdgcn_mfma_f32_16x16x32_bf16(a, b, c, 0, 0, 0);
}
__device__ __forceinline__ float frcp(float x) { return __builtin_amdgcn_rcpf(x); }
__device__ __forceinline__ void lds_barrier() {
    asm volatile("s_waitcnt lgkmcnt(0)\n\ts_barrier" ::: "memory");
}
// fp32 -> bf16 round-to-nearest-even (halves residual vs truncation)
__device__ __forceinline__ short bf16rne(float v) {
    unsigned u = __float_as_uint(v);
    unsigned r = u + 0x7FFFu + ((u >> 16) & 1u);
    return (short)(r >> 16);
}
// fp32 -> bf16 hi/lo split, RNE both parts (hi best single approx; lo residual)
__device__ __forceinline__ void bf16split(float v, short& hi, short& lo) {
    hi = bf16rne(v);
    float hf = __uint_as_float(((unsigned)(unsigned short)hi) << 16);
    lo = bf16rne(v - hf);
}

// MFMA LSTM, 2-TERM precision split (Whi.Shi + Whi.Slo = Whi.S, RNE weights;
// the Wlo.Shi term is dropped -> frees 64 weight VGPRs so the working set
// (~208 unified regs) fits TWO waves/SIMD). Grid = 512 blocks = 4 layers x
// 128 groups of 2 batches -> 2 blocks/CU forced co-residency = two
// INDEPENDENT barrier domains per CU (the R9 lever; R16 proved co-residency
// happens but spilled at 128-reg cap with 3-term weights — this is that
// experiment without the spill). MFMA uses 2/16 B-cols (latency-bound, FLOP
// waste irrelevant). CH=4: 46 KB LDS/block, 2 blocks fit. x cols n>=2 stay
// zero; h-plane writes forced zero for n>=2.
__global__ __attribute__((amdgpu_flat_work_group_size(NT, NT), amdgpu_waves_per_eu(2)))
void lstm_mfma(const float* __restrict__ xg,    // x [B][T][6]
               const float* __restrict__ Wih0,  // [256][6]
               const float* __restrict__ WihR,  // [3][256][64]
               const float* __restrict__ Whh4,  // [4][256][64]
               const float* __restrict__ bih4,  // [4][256]
               const float* __restrict__ bhh4,  // [4][256]
               float* __restrict__ seq)         // [T][B][64] in-place
{
    const int bid = blockIdx.x;
    const int l   = bid >> 7;        // layer-major dispatch: producers first
    const int gb  = bid & (NG - 1);
    const int b0  = gb << 1;         // 2 batches per group
    const bool FIRST = (l == 0);
    const bool LAST  = (l == 3);
    const float* Wih = FIRST ? Wih0 : (WihR + (size_t)(l - 1) * 256 * HH);
    const float* Whh = Whh4 + (size_t)l * 256 * HH;
    int* const fin  = &g_flags[(l - 1) * NG + gb];  // deref only if l>0
    int* const fout = &g_flags[l * NG + gb];        // deref only if l<3

    const int tid = threadIdx.x;
    const int w   = tid >> 6;        // wave 0..3
    const int ln  = tid & 63;
    const int n   = ln & 15;         // batch col (0..15; 0-1 real)
    const int g4  = ln >> 4;         // 0..3
    const int k0  = (w << 4) + (g4 << 2);  // this lane's unit base (4 units)

    // LDS planes (bf16), row width 72 (pad). 46080 B -> 2 blocks/CU fit.
    __shared__ __align__(16) unsigned short xhi[2][CH][16][72];
    __shared__ __align__(16) unsigned short xlo[2][CH][16][72];
    __shared__ __align__(16) unsigned short hhi[2][16][72];
    __shared__ __align__(16) unsigned short hlo[2][16][72];

    // ---- weight A-fragments: whi[tile q][kstep s] ONLY (2-term split) ----
    short8 whi[4][4];
#pragma unroll
    for (int q = 0; q < 4; ++q) {
        const float sc = (q == 2) ? (-2.f * LOG2E) : (-LOG2E);
        const int gr = (q << 6) + (w << 4) + n;   // gate row of tile q
#pragma unroll
        for (int s = 0; s < 4; ++s) {
            const int kb = s * 32 + g4 * 8;
            short8 hi;
#pragma unroll
            for (int i = 0; i < 8; ++i) {
                const int k = kb + i;
                float v;
                if (k < 64)      v = Whh[gr * 64 + k];
                else if (!FIRST) v = Wih[gr * 64 + (k - 64)];
                else             v = (k - 64 < 6) ? Wih[gr * 6 + (k - 64)] : 0.f;
                hi[i] = bf16rne(v * sc);
            }
            whi[q][s] = hi;
        }
    }
    // bias -> C init (row r of tile q = gate 64q + k0 + r)
    floatx4 bias[4];
#pragma unroll
    for (int q = 0; q < 4; ++q) {
        const float sc = (q == 2) ? (-2.f * LOG2E) : (-LOG2E);
#pragma unroll
        for (int r = 0; r < 4; ++r) {
            const int gr = (q << 6) + k0 + r;
            bias[q][r] = (bih4[l * 256 + gr] + bhh4[l * 256 + gr]) * sc;
        }
    }

    // zero LDS (h(-1)=0; x cols n>=2 / layer0 cols>=6 stay 0 forever)
    {
        unsigned short* p0 = &xhi[0][0][0][0];
        unsigned short* p1 = &xlo[0][0][0][0];
        for (int i = tid; i < 2 * CH * 16 * 72; i += NT) { p0[i] = 0; p1[i] = 0; }
        unsigned short* p2 = &hhi[0][0][0];
        unsigned short* p3 = &hlo[0][0][0];
        for (int i = tid; i < 2 * 16 * 72; i += NT) { p2[i] = 0; p3[i] = 0; }
    }
    __syncthreads();

    // staging map (layers>=1): tt = row 0..3, c4 = batch slot (<2 active),
    // kh = float4 col base. layer0: tid<8 -> (ttf = tid>>1, nf = tid&1).
    const int tt = tid >> 6;
    const int c4 = (tid >> 4) & 3;
    const int kh = (tid & 15) << 2;
    const int ttf = tid >> 1;
    const int nf  = tid & 1;

    // ---- wait for producer chunk 0, stage it into buf 0 ----
    if (!FIRST) {
        if (tid == 0)
            while (__hip_atomic_load(fin, __ATOMIC_ACQUIRE, __HIP_MEMORY_SCOPE_AGENT) < 1)
                __builtin_amdgcn_s_sleep(8);
        __syncthreads();
        if (c4 < 2) {
            const floatx4 v = *(const floatx4*)(seq + ((size_t)tt * BB + b0 + c4) * HH + kh);
            short4v hi4, lo4;
#pragma unroll
            for (int i = 0; i < 4; ++i) { short a, b2; bf16split(v[i], a, b2); hi4[i] = a; lo4[i] = b2; }
            *(short4v*)&xhi[0][tt][c4][kh] = hi4;
            *(short4v*)&xlo[0][tt][c4][kh] = lo4;
        }
    } else if (tid < 8) {
        const float* sx = xg + ((size_t)(b0 + nf) * TT + ttf) * 6;
#pragma unroll
        for (int i = 0; i < 6; ++i) {
            short a, b2; bf16split(sx[i], a, b2);
            xhi[0][ttf][nf][i] = (unsigned short)a;
            xlo[0][ttf][nf][i] = (unsigned short)b2;
        }
    }
    float c0 = 0.f, c1 = 0.f, c2 = 0.f, c3 = 0.f;
    __syncthreads();

    for (int ck = 0; ck < NCH; ++ck) {
        const int buf = ck & 1;
        const bool pfv = (ck + 1 < NCH);
        if (!FIRST && pfv) {   // producer must have published chunk ck+1
            if (tid == 0)
                while (__hip_atomic_load(fin, __ATOMIC_ACQUIRE, __HIP_MEMORY_SCOPE_AGENT) < ck + 2)
                    __builtin_amdgcn_s_sleep(8);
            __syncthreads();
        }
        floatx4 pv;
        float xv[6];

#pragma unroll
        for (int ph = 0; ph < CH; ++ph) {
            const int t = ck * CH + ph;
            if (ph == 0 && pfv) {   // issue next-chunk staging loads
                if (!FIRST) {
                    if (c4 < 2)
                        pv = *(const floatx4*)(seq + ((size_t)((ck + 1) * CH + tt) * BB + b0 + c4) * HH + kh);
                } else if (tid < 8) {
                    const float* sx = xg + ((size_t)(b0 + nf) * TT + (ck + 1) * CH + ttf) * 6;
#pragma unroll
                    for (int i = 0; i < 6; ++i) xv[i] = sx[i];
                }
            }

            // B fragments straight from LDS (layout == fragment)
            const short8 bx0 = *(const short8*)&xhi[buf][ph][n][g4 * 8];
            const short8 bx1 = *(const short8*)&xhi[buf][ph][n][32 + g4 * 8];
            const short8 by0 = *(const short8*)&xlo[buf][ph][n][g4 * 8];
            const short8 by1 = *(const short8*)&xlo[buf][ph][n][32 + g4 * 8];
            const int hb = (t + 1) & 1;   // h(t-1) lives in buf (t-1)&1
            const short8 bh0 = *(const short8*)&hhi[hb][n][g4 * 8];
            const short8 bh1 = *(const short8*)&hhi[hb][n][32 + g4 * 8];
            const short8 bl0 = *(const short8*)&hlo[hb][n][g4 * 8];
            const short8 bl1 = *(const short8*)&hlo[hb][n][32 + g4 * 8];

            // 2-term: Whi.Shi + Whi.Slo (Wlo term dropped -> 32 MFMA/step)
            floatx4 a0 = bias[0], a1 = bias[1], a2 = bias[2], a3 = bias[3];
#define TERM(bq0, bq1, bq2, bq3, W) \
            a0 = mfma16(W[0][0], bq0, a0); a1 = mfma16(W[1][0], bq0, a1); \
            a2 = mfma16(W[2][0], bq0, a2); a3 = mfma16(W[3][0], bq0, a3); \
            a0 = mfma16(W[0][1], bq1, a0); a1 = mfma16(W[1][1], bq1, a1); \
            a2 = mfma16(W[2][1], bq1, a2); a3 = mfma16(W[3][1], bq1, a3); \
            a0 = mfma16(W[0][2], bq2, a0); a1 = mfma16(W[1][2], bq2, a1); \
            a2 = mfma16(W[2][2], bq2, a2); a3 = mfma16(W[3][2], bq2, a3); \
            a0 = mfma16(W[0][3], bq3, a0); a1 = mfma16(W[1][3], bq3, a1); \
            a2 = mfma16(W[2][3], bq3, a2); a3 = mfma16(W[3][3], bq3, a3);
            TERM(bh0, bh1, bx0, bx1, whi)   // Whi . Shi
            TERM(bl0, bl1, by0, by1, whi)   // Whi . Slo
#undef TERM

            // lane-local epilogue: 4 units (i,f,g,o all in-register)
            floatx4 hv4;
            short4v h4hi, h4lo;
#define UNIT(r, cr) { \
            const float si = frcp(1.f + exp2f(a0[r])); \
            const float sf = frcp(1.f + exp2f(a1[r])); \
            const float tg = fmaf(2.f, frcp(1.f + exp2f(a2[r])), -1.f); \
            const float so = frcp(1.f + exp2f(a3[r])); \
            cr = fmaf(sf, cr, si * tg); \
            const float tc = fmaf(2.f, frcp(1.f + exp2f(cr * (-2.f * LOG2E))), -1.f); \
            const float hv = so * tc; \
            hv4[r] = hv; \
            short ha, hbs; bf16split(hv, ha, hbs); h4hi[r] = ha; h4lo[r] = hbs; }
            UNIT(0, c0) UNIT(1, c1) UNIT(2, c2) UNIT(3, c3)
#undef UNIT

            // h planes: zero for dummy cols n>=2 (keeps B operand clean)
            const short4v z4s = {0, 0, 0, 0};
            *(short4v*)&hhi[t & 1][n][k0] = (n < 2) ? h4hi : z4s;
            *(short4v*)&hlo[t & 1][n][k0] = (n < 2) ? h4lo : z4s;
            if ((!LAST || t == TT - 1) && n < 2)
                *(floatx4*)(seq + ((size_t)t * BB + b0 + n) * HH + k0) = hv4;

            // land next-chunk staging at ph2
            if (pfv && ph == 2) {
                if (!FIRST) {
                    if (c4 < 2) {
                        short4v hi4, lo4;
#pragma unroll
                        for (int i = 0; i < 4; ++i) { short a, b2; bf16split(pv[i], a, b2); hi4[i] = a; lo4[i] = b2; }
                        *(short4v*)&xhi[1 - buf][tt][c4][kh] = hi4;
                        *(short4v*)&xlo[1 - buf][tt][c4][kh] = lo4;
                    }
                } else if (tid < 8) {
#pragma unroll
                    for (int i = 0; i < 6; ++i) {
                        short a, b2; bf16split(xv[i], a, b2);
                        xhi[1 - buf][ttf][nf][i] = (unsigned short)a;
                        xlo[1 - buf][ttf][nf][i] = (unsigned short)b2;
                    }
                }
            }

            if (ph < CH - 1) lds_barrier();   // LDS-only sync (stores in flight)
            else             __syncthreads(); // chunk end: drains vm for publish
        }
        if (!LAST && tid == 0)
            __hip_atomic_store(fout, ck + 1, __ATOMIC_RELEASE, __HIP_MEMORY_SCOPE_AGENT);
    }
}

// out[b] = fc_b + sum_j relu(h[T-1][b][j]) * fc_w[j]
__global__ __launch_bounds__(256)
void fc_kernel(const float* __restrict__ seq, const float* __restrict__ fcw,
               const float* __restrict__ fcb, float* __restrict__ out)
{
    __shared__ float w[HH];
    const int tid = threadIdx.x;
    if (tid < HH) w[tid] = fcw[tid];
    __syncthreads();
    const float* h = &seq[((size_t)(TT - 1) * BB + tid) * HH];
    float s = fcb[0];
#pragma unroll
    for (int jj = 0; jj < HH; ++jj)
        s = fmaf(fmaxf(h[jj], 0.f), w[jj], s);
    out[tid] = s;
}

extern "C" void kernel_launch(void* const* d_in, const int* in_sizes, int n_in,
                              void* d_out, int out_size, void* d_ws, size_t ws_size,
                              hipStream_t stream) {
    const float* x    = (const float*)d_in[0];  // [B][T][6]
    const float* Wih0 = (const float*)d_in[1];  // [256][6]
    const float* WihR = (const float*)d_in[2];  // [3][256][64]
    const float* Whh  = (const float*)d_in[3];  // [4][256][64]
    const float* bih  = (const float*)d_in[4];  // [4][256]
    const float* bhh  = (const float*)d_in[5];  // [4][256]
    const float* fcw  = (const float*)d_in[6];  // [1][64]
    const float* fcb  = (const float*)d_in[7];  // [1]
    float* out = (float*)d_out;
    float* seq = (float*)d_ws;                  // [T][B][64] fp32 = 268 MB

    zero_flags_kernel<<<dim3(1), dim3(3 * NG), 0, stream>>>();
    lstm_mfma<<<dim3(4 * NG), dim3(NT), 0, stream>>>(x, Wih0, WihR, Whh, bih, bhh, seq);
    fc_kernel<<<dim3(1), dim3(256), 0, stream>>>(seq, fcw, fcb, out);
}

// Round 19
// 4468.864 us; speedup vs baseline: 2.6151x; 2.6151x over previous
//
#include <hip/hip_runtime.h>
#include <cstddef>

#define BB 256   // batch
#define TT 4096  // time steps
#define HH 64    // hidden
#define NT 256   // 4 waves; wave w owns units 16w..16w+15 (all 4 gates)
#define CH 8     // chunk depth (steps)
#define NCH (TT / CH)
#define NGB 16   // batch groups of 16
#define LOG2E 1.442695041f

typedef __attribute__((ext_vector_type(8))) short short8;   // 8 bf16 (4 VGPR)
typedef __attribute__((ext_vector_type(4))) short short4v;  // 4 bf16 (2 VGPR)
typedef __attribute__((ext_vector_type(4))) float floatx4;

// produced-chunk counters: consumer (l,gb) polls row l-1.
__device__ int g_flags[3 * NGB];
__global__ void zero_flags_kernel() { g_flags[threadIdx.x] = 0; }

__device__ __forceinline__ floatx4 mfma16(short8 a, short8 b, floatx4 c) {
    return __builtin_amdgcn_mfma_f32_16x16x32_bf16(a, b, c, 0, 0, 0);
}
__device__ __forceinline__ float frcp(float x) { return __builtin_amdgcn_rcpf(x); }
__device__ __forceinline__ void lds_barrier() {
    asm volatile("s_waitcnt lgkmcnt(0)\n\ts_barrier" ::: "memory");
}
// fp32 -> bf16 round-to-nearest-even
__device__ __forceinline__ short bf16rne(float v) {
    unsigned u = __float_as_uint(v);
    unsigned r = u + 0x7FFFu + ((u >> 16) & 1u);
    return (short)(r >> 16);
}
// fp32 -> bf16 hi/lo split, RNE both parts
__device__ __forceinline__ void bf16split(float v, short& hi, short& lo) {
    hi = bf16rne(v);
    float hf = __uint_as_float(((unsigned)(unsigned short)hi) << 16);
    lo = bf16rne(v - hf);
}

// MFMA LSTM: R12 structure (session-verified optimum, 4470us) with the
// R18-VALIDATED 2-term precision split: G = Whi.(Shi+Slo), RNE weights
// (Wlo.Shi dropped; R18 measured absmax 1.22e-4 vs 6.03e-4 threshold with
// identical per-batch arithmetic). 32 MFMA/step (was 48), -64 weight regs.
// Grid = 64 blocks = 4 layers x 16 batch-groups; wave w owns tiles
// {w,w+4,w+8,w+12} -> c/h update 100% lane-local; h/x as bf16 hi/lo LDS
// planes [n][72] whose ds_read_b128 IS the B-fragment; layer pipeline via
// chunk-granular acquire/release flags, seq in-place fp32.
// Eliminated by experiment: R13 acc-ILP (+9%), R14 x-hoist (+4%), R15
// shared-barrier dual-group (+73%), R16/R18 2-blocks/CU (+160%) — the step
// chain is serial-latency-bound; co-resident domains interfere, not overlap.
__global__ __attribute__((amdgpu_flat_work_group_size(NT, NT), amdgpu_waves_per_eu(1)))
void lstm_mfma(const float* __restrict__ xg,    // x [B][T][6]
               const float* __restrict__ Wih0,  // [256][6]
               const float* __restrict__ WihR,  // [3][256][64]
               const float* __restrict__ Whh4,  // [4][256][64]
               const float* __restrict__ bih4,  // [4][256]
               const float* __restrict__ bhh4,  // [4][256]
               float* __restrict__ seq)         // [T][B][64] in-place
{
    const int bid = blockIdx.x;
    const int l   = bid >> 4;
    const int gb  = bid & 15;
    const int b0  = gb << 4;
    const bool FIRST = (l == 0);
    const bool LAST  = (l == 3);
    const float* Wih = FIRST ? Wih0 : (WihR + (size_t)(l - 1) * 256 * HH);
    const float* Whh = Whh4 + (size_t)l * 256 * HH;
    int* const fin  = &g_flags[(l - 1) * NGB + gb];  // deref only if l>0
    int* const fout = &g_flags[l * NGB + gb];        // deref only if l<3

    const int tid = threadIdx.x;
    const int w   = tid >> 6;        // wave 0..3
    const int ln  = tid & 63;
    const int n   = ln & 15;         // batch col (B/C), also A-row for loads
    const int g4  = ln >> 4;         // 0..3
    const int k0  = (w << 4) + (g4 << 2);  // this lane's unit base (4 units)

    // LDS planes (bf16), row width 72 (pad)
    __shared__ __align__(16) unsigned short xhi[2][CH][16][72];
    __shared__ __align__(16) unsigned short xlo[2][CH][16][72];
    __shared__ __align__(16) unsigned short hhi[2][16][72];
    __shared__ __align__(16) unsigned short hlo[2][16][72];

    // ---- weight A-fragments: whi[tile q][kstep s] ONLY (2-term split) ----
    short8 whi[4][4];
#pragma unroll
    for (int q = 0; q < 4; ++q) {
        const float sc = (q == 2) ? (-2.f * LOG2E) : (-LOG2E);
        const int gr = (q << 6) + (w << 4) + n;   // gate row of tile q
#pragma unroll
        for (int s = 0; s < 4; ++s) {
            const int kb = s * 32 + g4 * 8;
            short8 hi;
#pragma unroll
            for (int i = 0; i < 8; ++i) {
                const int k = kb + i;
                float v;
                if (k < 64)      v = Whh[gr * 64 + k];
                else if (!FIRST) v = Wih[gr * 64 + (k - 64)];
                else             v = (k - 64 < 6) ? Wih[gr * 6 + (k - 64)] : 0.f;
                hi[i] = bf16rne(v * sc);
            }
            whi[q][s] = hi;
        }
    }
    // bias -> C init (row r of tile q = gate 64q + k0 + r)
    floatx4 bias[4];
#pragma unroll
    for (int q = 0; q < 4; ++q) {
        const float sc = (q == 2) ? (-2.f * LOG2E) : (-LOG2E);
#pragma unroll
        for (int r = 0; r < 4; ++r) {
            const int gr = (q << 6) + k0 + r;
            bias[q][r] = (bih4[l * 256 + gr] + bhh4[l * 256 + gr]) * sc;
        }
    }

    // zero LDS (h(-1)=0; x pads/layer0 cols>=6 stay 0)
    {
        unsigned short* p0 = &xhi[0][0][0][0];
        for (int i = tid; i < 2 * CH * 16 * 72; i += NT) { p0[i] = 0; (&xlo[0][0][0][0])[i] = 0; }
        unsigned short* p1 = &hhi[0][0][0];
        for (int i = tid; i < 2 * 16 * 72; i += NT) { p1[i] = 0; (&hlo[0][0][0])[i] = 0; }
    }
    __syncthreads();

    // staging map (layers>=1): thread -> (tt = tid>>5, sn = (tid>>1)&15, kh)
    const int tt = tid >> 5;
    const int sn = (tid >> 1) & 15;
    const int kh = (tid & 1) * 32;
    // layer0 map: tid<128 -> (ttf = tid>>4, nf = tid&15)
    const int ttf = tid >> 4;
    const int nf  = tid & 15;

    // ---- wait for producer chunk 0, stage it into buf 0 ----
    if (!FIRST) {
        if (tid == 0)
            while (__hip_atomic_load(fin, __ATOMIC_ACQUIRE, __HIP_MEMORY_SCOPE_AGENT) < 1)
                __builtin_amdgcn_s_sleep(8);
        __syncthreads();
        const float* src = seq + ((size_t)(0 * CH + tt) * BB + b0 + sn) * HH + kh;
        floatx4 pv[8];
#pragma unroll
        for (int m = 0; m < 8; ++m) pv[m] = ((const floatx4*)src)[m];
#pragma unroll
        for (int m = 0; m < 4; ++m) {
            short8 hi8, lo8;
#pragma unroll
            for (int i = 0; i < 8; ++i) {
                const float v = (i < 4) ? pv[2 * m][i] : pv[2 * m + 1][i - 4];
                short a, b2; bf16split(v, a, b2); hi8[i] = a; lo8[i] = b2;
            }
            *(short8*)&xhi[0][tt][sn][kh + 8 * m] = hi8;
            *(short8*)&xlo[0][tt][sn][kh + 8 * m] = lo8;
        }
    } else if (tid < 128) {
        const float* sx = xg + ((size_t)(b0 + nf) * TT + ttf) * 6;
#pragma unroll
        for (int i = 0; i < 6; ++i) {
            short a, b2; bf16split(sx[i], a, b2);
            xhi[0][ttf][nf][i] = (unsigned short)a;
            xlo[0][ttf][nf][i] = (unsigned short)b2;
        }
    }
    float c0 = 0.f, c1 = 0.f, c2 = 0.f, c3 = 0.f;
    __syncthreads();

    for (int ck = 0; ck < NCH; ++ck) {
        const int buf = ck & 1;
        const bool pfv = (ck + 1 < NCH);
        if (!FIRST && pfv) {   // producer must have published chunk ck+1
            if (tid == 0)
                while (__hip_atomic_load(fin, __ATOMIC_ACQUIRE, __HIP_MEMORY_SCOPE_AGENT) < ck + 2)
                    __builtin_amdgcn_s_sleep(8);
            __syncthreads();
        }
        floatx4 pv[8];
        float xv[6];

#pragma unroll
        for (int ph = 0; ph < CH; ++ph) {
            const int t = ck * CH + ph;
            if (ph == 0 && pfv) {   // issue next-chunk staging loads
                if (!FIRST) {
                    const float* src = seq + ((size_t)((ck + 1) * CH + tt) * BB + b0 + sn) * HH + kh;
#pragma unroll
                    for (int m = 0; m < 8; ++m) pv[m] = ((const floatx4*)src)[m];
                } else if (tid < 128) {
                    const float* sx = xg + ((size_t)(b0 + nf) * TT + (ck + 1) * CH + ttf) * 6;
#pragma unroll
                    for (int i = 0; i < 6; ++i) xv[i] = sx[i];
                }
            }

            // B fragments straight from LDS (layout == fragment)
            const int hb = (t + 1) & 1;   // h(t-1) lives in buf (t-1)&1
            const short8 bh0 = *(const short8*)&hhi[hb][n][g4 * 8];
            const short8 bh1 = *(const short8*)&hhi[hb][n][32 + g4 * 8];
            const short8 bl0 = *(const short8*)&hlo[hb][n][g4 * 8];
            const short8 bl1 = *(const short8*)&hlo[hb][n][32 + g4 * 8];
            const short8 bx0 = *(const short8*)&xhi[buf][ph][n][g4 * 8];
            const short8 bx1 = *(const short8*)&xhi[buf][ph][n][32 + g4 * 8];
            const short8 by0 = *(const short8*)&xlo[buf][ph][n][g4 * 8];
            const short8 by1 = *(const short8*)&xlo[buf][ph][n][32 + g4 * 8];

            // 2-term: Whi.Shi + Whi.Slo (R18-validated: absmax 1.22e-4)
            floatx4 a0 = bias[0], a1 = bias[1], a2 = bias[2], a3 = bias[3];
#define TERM(bq0, bq1, bq2, bq3, W) \
            a0 = mfma16(W[0][0], bq0, a0); a1 = mfma16(W[1][0], bq0, a1); \
            a2 = mfma16(W[2][0], bq0, a2); a3 = mfma16(W[3][0], bq0, a3); \
            a0 = mfma16(W[0][1], bq1, a0); a1 = mfma16(W[1][1], bq1, a1); \
            a2 = mfma16(W[2][1], bq1, a2); a3 = mfma16(W[3][1], bq1, a3); \
            a0 = mfma16(W[0][2], bq2, a0); a1 = mfma16(W[1][2], bq2, a1); \
            a2 = mfma16(W[2][2], bq2, a2); a3 = mfma16(W[3][2], bq2, a3); \
            a0 = mfma16(W[0][3], bq3, a0); a1 = mfma16(W[1][3], bq3, a1); \
            a2 = mfma16(W[2][3], bq3, a2); a3 = mfma16(W[3][3], bq3, a3);
            TERM(bh0, bh1, bx0, bx1, whi)   // Whi . Shi
            TERM(bl0, bl1, by0, by1, whi)   // Whi . Slo
#undef TERM

            // lane-local epilogue: 4 units (i,f,g,o all in-register)
            floatx4 hv4;
            short4v h4hi, h4lo;
#define UNIT(r, cr) { \
            const float si = frcp(1.f + exp2f(a0[r])); \
            const float sf = frcp(1.f + exp2f(a1[r])); \
            const float tg = fmaf(2.f, frcp(1.f + exp2f(a2[r])), -1.f); \
            const float so = frcp(1.f + exp2f(a3[r])); \
            cr = fmaf(sf, cr, si * tg); \
            const float tc = fmaf(2.f, frcp(1.f + exp2f(cr * (-2.f * LOG2E))), -1.f); \
            const float hv = so * tc; \
            hv4[r] = hv; \
            short ha, hbs; bf16split(hv, ha, hbs); h4hi[r] = ha; h4lo[r] = hbs; }
            UNIT(0, c0) UNIT(1, c1) UNIT(2, c2) UNIT(3, c3)
#undef UNIT

            // h planes (next step's B) + fp32 h to seq (pipeline medium)
            *(short4v*)&hhi[t & 1][n][k0] = h4hi;
            *(short4v*)&hlo[t & 1][n][k0] = h4lo;
            if (!LAST || t == TT - 1)
                *(floatx4*)(seq + ((size_t)t * BB + b0 + n) * HH + k0) = hv4;

            // land next-chunk staging (convert + plane writes), spread over phs
            if (pfv) {
                if (!FIRST) {
                    if (ph >= 4) {
                        const int m = ph - 4;
                        short8 hi8, lo8;
#pragma unroll
                        for (int i = 0; i < 8; ++i) {
                            const float v = (i < 4) ? pv[2 * m][i] : pv[2 * m + 1][i - 4];
                            short a, b2; bf16split(v, a, b2); hi8[i] = a; lo8[i] = b2;
                        }
                        *(short8*)&xhi[1 - buf][tt][sn][kh + 8 * m] = hi8;
                        *(short8*)&xlo[1 - buf][tt][sn][kh + 8 * m] = lo8;
                    }
                } else if (ph == 2 && tid < 128) {
#pragma unroll
                    for (int i = 0; i < 6; ++i) {
                        short a, b2; bf16split(xv[i], a, b2);
                        xhi[1 - buf][ttf][nf][i] = (unsigned short)a;
                        xlo[1 - buf][ttf][nf][i] = (unsigned short)b2;
                    }
                }
            }

            if (ph < CH - 1) lds_barrier();   // LDS-only sync (stores in flight)
            else             __syncthreads(); // chunk end: drains vm for publish
        }
        if (!LAST && tid == 0)
            __hip_atomic_store(fout, ck + 1, __ATOMIC_RELEASE, __HIP_MEMORY_SCOPE_AGENT);
    }
}

// out[b] = fc_b + sum_j relu(h[T-1][b][j]) * fc_w[j]
__global__ __launch_bounds__(256)
void fc_kernel(const float* __restrict__ seq, const float* __restrict__ fcw,
               const float* __restrict__ fcb, float* __restrict__ out)
{
    __shared__ float w[HH];
    const int tid = threadIdx.x;
    if (tid < HH) w[tid] = fcw[tid];
    __syncthreads();
    const float* h = &seq[((size_t)(TT - 1) * BB + tid) * HH];
    float s = fcb[0];
#pragma unroll
    for (int jj = 0; jj < HH; ++jj)
        s = fmaf(fmaxf(h[jj], 0.f), w[jj], s);
    out[tid] = s;
}

extern "C" void kernel_launch(void* const* d_in, const int* in_sizes, int n_in,
                              void* d_out, int out_size, void* d_ws, size_t ws_size,
                              hipStream_t stream) {
    const float* x    = (const float*)d_in[0];  // [B][T][6]
    const float* Wih0 = (const float*)d_in[1];  // [256][6]
    const float* WihR = (const float*)d_in[2];  // [3][256][64]
    const float* Whh  = (const float*)d_in[3];  // [4][256][64]
    const float* bih  = (const float*)d_in[4];  // [4][256]
    const float* bhh  = (const float*)d_in[5];  // [4][256]
    const float* fcw  = (const float*)d_in[6];  // [1][64]
    const float* fcb  = (const float*)d_in[7];  // [1]
    float* out = (float*)d_out;
    float* seq = (float*)d_ws;                  // [T][B][64] fp32 = 268 MB

    zero_flags_kernel<<<dim3(1), dim3(3 * NGB), 0, stream>>>();
    lstm_mfma<<<dim3(4 * NGB), dim3(NT), 0, stream>>>(x, Wih0, WihR, Whh, bih, bhh, seq);
    fc_kernel<<<dim3(1), dim3(256), 0, stream>>>(seq, fcw, fcb, out);
}